// Round 3
// baseline (370.907 us; speedup 1.0000x reference)
//
#include <hip/hip_runtime.h>

#define N0        200000
#define N1        25000
#define N2        5000
#define FANOUT    16
#define IN_FEATS  500
#define NH        128
#define NC        47
#define K_PAD     512

typedef __attribute__((ext_vector_type(4))) float f32x4;
typedef __attribute__((ext_vector_type(8))) short bf16x8;
typedef __attribute__((ext_vector_type(4))) unsigned int uint4_;

__device__ __forceinline__ unsigned short f2bf(float f) {
    unsigned int u = __builtin_bit_cast(unsigned int, f);
    u += 0x7fffu + ((u >> 16) & 1u);          // RNE
    return (unsigned short)(u >> 16);
}
__device__ __forceinline__ float bf2f(unsigned short h) {
    unsigned int u = ((unsigned int)h) << 16;
    return __builtin_bit_cast(float, u);
}

// ---------------------------------------------------------------------------
// k0: Wt[c][k] = bf16(W1[k][c]), zero-padded to K_PAD. 8 blocks, tiny.
// ---------------------------------------------------------------------------
__global__ __launch_bounds__(256) void k0_transpose(
    const float* __restrict__ W1, unsigned short* __restrict__ Wt)
{
    __shared__ unsigned short sm[64][NH];
    const int t = threadIdx.x;
    const int kbase = blockIdx.x * 64;

    for (int r = t >> 7; r < 64; r += 2) {
        const int k = kbase + r;
        const int c = t & (NH - 1);
        sm[r][c] = f2bf(k < IN_FEATS ? W1[(size_t)k * NH + c] : 0.f);
    }
    __syncthreads();

    const int c  = t >> 1;
    const int ko = (t & 1) * 32;
    unsigned short* dst = Wt + (size_t)c * K_PAD + kbase + ko;
    #pragma unroll
    for (int i = 0; i < 32; i += 8) {
        bf16x8 v;
        #pragma unroll
        for (int e = 0; e < 8; ++e) v[e] = (short)sm[ko + i + e][c];
        *(bf16x8*)(dst + i) = v;
    }
}

// ---------------------------------------------------------------------------
// k1_fused: gather-mean -> LDS A-tile (bf16, XOR-swizzled) -> MFMA with
// B-fragments straight from global Wt -> h1cat = [h, relu(h)] bf16.
// Block: 256 thr (4 waves), 64 rows; wave owns 16 rows x 128 cols.
// ---------------------------------------------------------------------------
__global__ __launch_bounds__(256) void k1_fused(
    const float* __restrict__ features,       // [N0, IN_FEATS]
    const int*   __restrict__ src0,           // [N1, FANOUT]
    const unsigned short* __restrict__ Wt,    // [NH, K_PAD] bf16
    const float* __restrict__ b1,             // [NH]
    unsigned short* __restrict__ h1cat)       // [N1, 2*NH] bf16
{
    __shared__ unsigned short A[64 * K_PAD];  // 64 KB, swizzled rows

    const int tid  = threadIdx.x;
    const int lane = tid & 63;
    const int wv   = tid >> 6;                // 0..3
    const int l15  = lane & 15;
    const int lq   = lane >> 4;               // 0..3
    const int rowbase = blockIdx.x * 64;

    // ---- Phase A: gather-mean, 16 rows per wave, lane covers 8 feats ----
    const int f0 = lane * 8;
    const bool v1 = (f0 + 7 < IN_FEATS);
    const bool v0 = (f0 < IN_FEATS);

    for (int r = 0; r < 16; ++r) {
        const int rl  = wv * 16 + r;
        const int row = rowbase + rl;
        float acc[8] = {0.f,0.f,0.f,0.f,0.f,0.f,0.f,0.f};
        if (row < N1) {
            const int rb = __builtin_amdgcn_readfirstlane(row) * FANOUT;
            #pragma unroll
            for (int j = 0; j < FANOUT; ++j) {
                const int nb = src0[rb + j];
                const float* p = features + (size_t)nb * IN_FEATS + f0;
                if (v1) {
                    f32x4 a = *(const f32x4*)p;
                    f32x4 b = *(const f32x4*)(p + 4);
                    acc[0] += a.x; acc[1] += a.y; acc[2] += a.z; acc[3] += a.w;
                    acc[4] += b.x; acc[5] += b.y; acc[6] += b.z; acc[7] += b.w;
                } else if (v0) {
                    f32x4 a = *(const f32x4*)p;
                    acc[0] += a.x; acc[1] += a.y; acc[2] += a.z; acc[3] += a.w;
                }
            }
        }
        unsigned int w0 = (unsigned int)f2bf(acc[0] * 0.0625f) | ((unsigned int)f2bf(acc[1] * 0.0625f) << 16);
        unsigned int w1 = (unsigned int)f2bf(acc[2] * 0.0625f) | ((unsigned int)f2bf(acc[3] * 0.0625f) << 16);
        unsigned int w2 = (unsigned int)f2bf(acc[4] * 0.0625f) | ((unsigned int)f2bf(acc[5] * 0.0625f) << 16);
        unsigned int w3 = (unsigned int)f2bf(acc[6] * 0.0625f) | ((unsigned int)f2bf(acc[7] * 0.0625f) << 16);
        uint4_ pack = {w0, w1, w2, w3};
        const int boff = rl * 1024 + ((f0 * 2) ^ ((rl & 7) << 4));   // byte offset
        *(uint4_*)((char*)A + boff) = pack;
    }
    __syncthreads();

    // ---- Phase B: 16 rows x 128 cols per wave, K=512 in 16 steps of 32 ----
    f32x4 acc2[8];
    #pragma unroll
    for (int n = 0; n < 8; ++n) acc2[n] = (f32x4){0.f,0.f,0.f,0.f};

    const int arow = wv * 16 + l15;
    const int arow_base = arow * 1024;
    const int aswz = (arow & 7) << 4;

    for (int kk = 0; kk < 16; ++kk) {
        const int ke = kk * 32 + lq * 8;      // element offset in [0, K_PAD)
        bf16x8 a = *(const bf16x8*)((const char*)A + arow_base + ((ke * 2) ^ aswz));
        #pragma unroll
        for (int nt = 0; nt < 8; ++nt) {
            const int col = nt * 16 + l15;
            bf16x8 b = *(const bf16x8*)(Wt + (size_t)col * K_PAD + ke);
            acc2[nt] = __builtin_amdgcn_mfma_f32_16x16x32_bf16(a, b, acc2[nt], 0, 0, 0);
        }
    }

    // ---- Epilogue: bias + concat(h, relu(h)) ----
    #pragma unroll
    for (int nt = 0; nt < 8; ++nt) {
        const int col  = nt * 16 + l15;
        const float bias = b1[col];
        #pragma unroll
        for (int rr = 0; rr < 4; ++rr) {
            const int row = rowbase + wv * 16 + lq * 4 + rr;
            if (row < N1) {
                const float h = acc2[nt][rr] + bias;
                h1cat[(size_t)row * 256 + col]       = f2bf(h);
                h1cat[(size_t)row * 256 + 128 + col] = f2bf(h > 0.f ? h : 0.f);
            }
        }
    }
}

// ---------------------------------------------------------------------------
// k2: gather-mean over bf16 h1cat + f32 GEMM [8x256]@[256x47] + bias.
// ---------------------------------------------------------------------------
__global__ __launch_bounds__(256) void k2_fused(
    const unsigned short* __restrict__ h1cat, // [N1, 256] bf16
    const int*   __restrict__ src1,           // [N2, FANOUT]
    const float* __restrict__ W2,             // [256, NC]
    const float* __restrict__ b2,             // [NC]
    float*       __restrict__ out)            // [N2, NC]
{
    __shared__ float sm[8][256];

    const int tid = threadIdx.x;
    const int r   = tid >> 5;
    const int s   = tid & 31;
    const int row = blockIdx.x * 8 + r;

    float acc[8] = {0.f,0.f,0.f,0.f,0.f,0.f,0.f,0.f};
    #pragma unroll
    for (int j = 0; j < FANOUT; ++j) {
        const int nb = src1[row * FANOUT + j];
        bf16x8 v = *(const bf16x8*)(h1cat + (size_t)nb * 256 + s * 8);
        #pragma unroll
        for (int e = 0; e < 8; ++e) acc[e] += bf2f((unsigned short)v[e]);
    }
    #pragma unroll
    for (int e = 0; e < 8; ++e) sm[r][s * 8 + e] = acc[e] * 0.0625f;
    __syncthreads();

    const int c0 = s, c1 = s + 32;
    float o0 = b2[c0];
    float o1 = (c1 < NC) ? b2[c1] : 0.f;
    for (int k = 0; k < 256; k += 4) {
        f32x4 mv = *(const f32x4*)&sm[r][k];
        #pragma unroll
        for (int e = 0; e < 4; ++e) {
            const float* wrow = W2 + (size_t)(k + e) * NC;
            o0 += mv[e] * wrow[c0];
            if (c1 < NC) o1 += mv[e] * wrow[c1];
        }
    }
    out[(size_t)row * NC + c0] = o0;
    if (c1 < NC) out[(size_t)row * NC + c1] = o1;
}

extern "C" void kernel_launch(void* const* d_in, const int* in_sizes, int n_in,
                              void* d_out, int out_size, void* d_ws, size_t ws_size,
                              hipStream_t stream)
{
    const float* features = (const float*)d_in[0];
    const int*   src0     = (const int*)  d_in[1];
    const int*   src1     = (const int*)  d_in[2];
    const float* W1       = (const float*)d_in[3];
    const float* b1       = (const float*)d_in[4];
    const float* W2       = (const float*)d_in[5];
    const float* b2       = (const float*)d_in[6];
    float*       out      = (float*)d_out;

    unsigned short* Wt    = (unsigned short*)d_ws;        // [NH][K_PAD] = 128 KB
    unsigned short* h1cat = Wt + (size_t)NH * K_PAD;      // [N1][256] bf16 = 12.8 MB

    hipLaunchKernelGGL(k0_transpose, dim3(K_PAD / 64), dim3(256), 0, stream, W1, Wt);
    hipLaunchKernelGGL(k1_fused, dim3((N1 + 63) / 64), dim3(256), 0, stream,
                       features, src0, Wt, b1, h1cat);
    hipLaunchKernelGGL(k2_fused, dim3(N2 / 8), dim3(256), 0, stream,
                       h1cat, src1, W2, b2, out);
}

// Round 4
// 252.905 us; speedup vs baseline: 1.4666x; 1.4666x over previous
//
#include <hip/hip_runtime.h>

#define N0        200000
#define N1        25000
#define N2        5000
#define FANOUT    16
#define IN_FEATS  500
#define NH        128
#define NC        47
#define K_PAD     512
#define ROWS      16          // rows per block in k1 (16 KB LDS tile)

typedef __attribute__((ext_vector_type(4))) float f32x4;
typedef __attribute__((ext_vector_type(8))) short bf16x8;
typedef __attribute__((ext_vector_type(4))) unsigned int uint4_;

__device__ __forceinline__ unsigned short f2bf(float f) {
    unsigned int u = __builtin_bit_cast(unsigned int, f);
    u += 0x7fffu + ((u >> 16) & 1u);          // RNE
    return (unsigned short)(u >> 16);
}
__device__ __forceinline__ float bf2f(unsigned short h) {
    unsigned int u = ((unsigned int)h) << 16;
    return __builtin_bit_cast(float, u);
}

// ---------------------------------------------------------------------------
// k0: Wt[c][k] = bf16(W1[k][c]), zero-padded to K_PAD.
// ---------------------------------------------------------------------------
__global__ __launch_bounds__(256) void k0_transpose(
    const float* __restrict__ W1, unsigned short* __restrict__ Wt)
{
    __shared__ unsigned short sm[64][NH];
    const int t = threadIdx.x;
    const int kbase = blockIdx.x * 64;

    for (int r = t >> 7; r < 64; r += 2) {
        const int k = kbase + r;
        const int c = t & (NH - 1);
        sm[r][c] = f2bf(k < IN_FEATS ? W1[(size_t)k * NH + c] : 0.f);
    }
    __syncthreads();

    const int c  = t >> 1;
    const int ko = (t & 1) * 32;
    unsigned short* dst = Wt + (size_t)c * K_PAD + kbase + ko;
    #pragma unroll
    for (int i = 0; i < 32; i += 8) {
        bf16x8 v;
        #pragma unroll
        for (int e = 0; e < 8; ++e) v[e] = (short)sm[ko + i + e][c];
        *(bf16x8*)(dst + i) = v;
    }
}

// ---------------------------------------------------------------------------
// k1_fused: gather-mean -> 16-row LDS A-tile (bf16, XOR-swizzled) -> MFMA
// (B straight from global Wt, L2-resident) -> h1cat = [h, relu(h)] bf16.
// 256 thr / 4 waves; wave gathers 4 rows, then computes 16 rows x 32 cols.
// Small LDS + capped VGPR -> ~16 waves/CU for gather concurrency.
// ---------------------------------------------------------------------------
__global__ __launch_bounds__(256, 4) void k1_fused(
    const float* __restrict__ features,       // [N0, IN_FEATS]
    const int*   __restrict__ src0,           // [N1, FANOUT]
    const unsigned short* __restrict__ Wt,    // [NH, K_PAD] bf16
    const float* __restrict__ b1,             // [NH]
    unsigned short* __restrict__ h1cat)       // [N1, 2*NH] bf16
{
    __shared__ unsigned short A[ROWS * K_PAD];  // 16 KB, swizzled rows

    const int tid  = threadIdx.x;
    const int lane = tid & 63;
    const int wv   = tid >> 6;                // 0..3
    const int l15  = lane & 15;
    const int lq   = lane >> 4;               // 0..3
    const int rowbase = blockIdx.x * ROWS;

    // ---- Phase A: gather-mean, 4 rows per wave, lane covers 8 feats ----
    const int f0 = lane * 8;
    const bool v1 = (f0 + 7 < IN_FEATS);
    const bool v0 = (f0 < IN_FEATS);

    #pragma unroll
    for (int r = 0; r < 4; ++r) {
        const int rl  = wv * 4 + r;
        const int row = rowbase + rl;
        float acc[8] = {0.f,0.f,0.f,0.f,0.f,0.f,0.f,0.f};
        if (row < N1) {
            const int rb = __builtin_amdgcn_readfirstlane(row) * FANOUT;
            #pragma unroll
            for (int j = 0; j < FANOUT; ++j) {
                const int nb = src0[rb + j];
                const float* p = features + (size_t)nb * IN_FEATS + f0;
                if (v1) {
                    f32x4 a = *(const f32x4*)p;
                    f32x4 b = *(const f32x4*)(p + 4);
                    acc[0] += a.x; acc[1] += a.y; acc[2] += a.z; acc[3] += a.w;
                    acc[4] += b.x; acc[5] += b.y; acc[6] += b.z; acc[7] += b.w;
                } else if (v0) {
                    f32x4 a = *(const f32x4*)p;
                    acc[0] += a.x; acc[1] += a.y; acc[2] += a.z; acc[3] += a.w;
                }
            }
        }
        unsigned int w0 = (unsigned int)f2bf(acc[0] * 0.0625f) | ((unsigned int)f2bf(acc[1] * 0.0625f) << 16);
        unsigned int w1 = (unsigned int)f2bf(acc[2] * 0.0625f) | ((unsigned int)f2bf(acc[3] * 0.0625f) << 16);
        unsigned int w2 = (unsigned int)f2bf(acc[4] * 0.0625f) | ((unsigned int)f2bf(acc[5] * 0.0625f) << 16);
        unsigned int w3 = (unsigned int)f2bf(acc[6] * 0.0625f) | ((unsigned int)f2bf(acc[7] * 0.0625f) << 16);
        uint4_ pack = {w0, w1, w2, w3};
        const int boff = rl * 1024 + ((f0 * 2) ^ ((rl & 7) << 4));   // byte offset
        *(uint4_*)((char*)A + boff) = pack;
    }
    __syncthreads();

    // ---- Phase B: all 16 rows x 32 cols per wave (cols wv*32..wv*32+31) ----
    f32x4 acc2[2];
    acc2[0] = (f32x4){0.f,0.f,0.f,0.f};
    acc2[1] = (f32x4){0.f,0.f,0.f,0.f};

    const int arow_base = l15 * 1024;
    const int aswz = (l15 & 7) << 4;

    #pragma unroll 4
    for (int kk = 0; kk < 16; ++kk) {
        const int ke = kk * 32 + lq * 8;      // element offset in [0, K_PAD)
        bf16x8 a = *(const bf16x8*)((const char*)A + arow_base + ((ke * 2) ^ aswz));
        #pragma unroll
        for (int nt = 0; nt < 2; ++nt) {
            const int col = wv * 32 + nt * 16 + l15;
            bf16x8 b = *(const bf16x8*)(Wt + (size_t)col * K_PAD + ke);
            acc2[nt] = __builtin_amdgcn_mfma_f32_16x16x32_bf16(a, b, acc2[nt], 0, 0, 0);
        }
    }

    // ---- Epilogue: bias + concat(h, relu(h)) ----
    #pragma unroll
    for (int nt = 0; nt < 2; ++nt) {
        const int col  = wv * 32 + nt * 16 + l15;
        const float bias = b1[col];
        #pragma unroll
        for (int rr = 0; rr < 4; ++rr) {
            const int row = rowbase + lq * 4 + rr;
            if (row < N1) {
                const float h = acc2[nt][rr] + bias;
                h1cat[(size_t)row * 256 + col]       = f2bf(h);
                h1cat[(size_t)row * 256 + 128 + col] = f2bf(h > 0.f ? h : 0.f);
            }
        }
    }
}

// ---------------------------------------------------------------------------
// k2: gather-mean over bf16 h1cat + f32 GEMM [8x256]@[256x47] + bias.
// ---------------------------------------------------------------------------
__global__ __launch_bounds__(256) void k2_fused(
    const unsigned short* __restrict__ h1cat, // [N1, 256] bf16
    const int*   __restrict__ src1,           // [N2, FANOUT]
    const float* __restrict__ W2,             // [256, NC]
    const float* __restrict__ b2,             // [NC]
    float*       __restrict__ out)            // [N2, NC]
{
    __shared__ float sm[8][256];

    const int tid = threadIdx.x;
    const int r   = tid >> 5;
    const int s   = tid & 31;
    const int row = blockIdx.x * 8 + r;

    float acc[8] = {0.f,0.f,0.f,0.f,0.f,0.f,0.f,0.f};
    #pragma unroll
    for (int j = 0; j < FANOUT; ++j) {
        const int nb = src1[row * FANOUT + j];
        bf16x8 v = *(const bf16x8*)(h1cat + (size_t)nb * 256 + s * 8);
        #pragma unroll
        for (int e = 0; e < 8; ++e) acc[e] += bf2f((unsigned short)v[e]);
    }
    #pragma unroll
    for (int e = 0; e < 8; ++e) sm[r][s * 8 + e] = acc[e] * 0.0625f;
    __syncthreads();

    const int c0 = s, c1 = s + 32;
    float o0 = b2[c0];
    float o1 = (c1 < NC) ? b2[c1] : 0.f;
    for (int k = 0; k < 256; k += 4) {
        f32x4 mv = *(const f32x4*)&sm[r][k];
        #pragma unroll
        for (int e = 0; e < 4; ++e) {
            const float* wrow = W2 + (size_t)(k + e) * NC;
            o0 += mv[e] * wrow[c0];
            if (c1 < NC) o1 += mv[e] * wrow[c1];
        }
    }
    out[(size_t)row * NC + c0] = o0;
    if (c1 < NC) out[(size_t)row * NC + c1] = o1;
}

extern "C" void kernel_launch(void* const* d_in, const int* in_sizes, int n_in,
                              void* d_out, int out_size, void* d_ws, size_t ws_size,
                              hipStream_t stream)
{
    const float* features = (const float*)d_in[0];
    const int*   src0     = (const int*)  d_in[1];
    const int*   src1     = (const int*)  d_in[2];
    const float* W1       = (const float*)d_in[3];
    const float* b1       = (const float*)d_in[4];
    const float* W2       = (const float*)d_in[5];
    const float* b2       = (const float*)d_in[6];
    float*       out      = (float*)d_out;

    unsigned short* Wt    = (unsigned short*)d_ws;        // [NH][K_PAD] = 128 KB
    unsigned short* h1cat = Wt + (size_t)NH * K_PAD;      // [N1][256] bf16 = 12.8 MB

    hipLaunchKernelGGL(k0_transpose, dim3(K_PAD / 64), dim3(256), 0, stream, W1, Wt);
    hipLaunchKernelGGL(k1_fused, dim3((N1 + ROWS - 1) / ROWS), dim3(256), 0, stream,
                       features, src0, Wt, b1, h1cat);
    hipLaunchKernelGGL(k2_fused, dim3(N2 / 8), dim3(256), 0, stream,
                       h1cat, src1, W2, b2, out);
}

// Round 5
// 249.251 us; speedup vs baseline: 1.4881x; 1.0147x over previous
//
#include <hip/hip_runtime.h>

#define N0        200000
#define N1        25000
#define N2        5000
#define FANOUT    16
#define IN_FEATS  500
#define NH        128
#define NC        47
#define K_PAD     512
#define ROWS      16          // rows per block in k1 (16 KB LDS tile)

typedef __attribute__((ext_vector_type(4))) float f32x4;
typedef __attribute__((ext_vector_type(8))) short bf16x8;
typedef __attribute__((ext_vector_type(4))) unsigned int uint4_;

__device__ __forceinline__ unsigned short f2bf(float f) {
    unsigned int u = __builtin_bit_cast(unsigned int, f);
    u += 0x7fffu + ((u >> 16) & 1u);          // RNE
    return (unsigned short)(u >> 16);
}
__device__ __forceinline__ float bfhi(unsigned int u) {   // high bf16 of a packed pair
    return __builtin_bit_cast(float, u & 0xffff0000u);
}
__device__ __forceinline__ float bflo(unsigned int u) {   // low bf16 of a packed pair
    return __builtin_bit_cast(float, u << 16);
}

// ---------------------------------------------------------------------------
// k_conv: features f32 [N0,500] -> fb bf16 [N0,512] (zero-padded).
// Pure streaming; nontemporal reads keep L3 for the bf16 table.
// One wave per row, 4 rows per block.
// ---------------------------------------------------------------------------
__global__ __launch_bounds__(256) void k_conv(
    const float* __restrict__ features, unsigned short* __restrict__ fb)
{
    const int lane = threadIdx.x & 63;
    const int row  = blockIdx.x * 4 + (threadIdx.x >> 6);   // grid covers N0 exactly
    const int f0   = lane * 8;

    float v[8] = {0.f,0.f,0.f,0.f,0.f,0.f,0.f,0.f};
    const float* p = features + (size_t)row * IN_FEATS + f0;
    if (f0 + 7 < IN_FEATS) {
        f32x4 a = __builtin_nontemporal_load((const f32x4*)p);
        f32x4 b = __builtin_nontemporal_load((const f32x4*)(p + 4));
        v[0]=a.x; v[1]=a.y; v[2]=a.z; v[3]=a.w;
        v[4]=b.x; v[5]=b.y; v[6]=b.z; v[7]=b.w;
    } else if (f0 < IN_FEATS) {
        f32x4 a = __builtin_nontemporal_load((const f32x4*)p);
        v[0]=a.x; v[1]=a.y; v[2]=a.z; v[3]=a.w;
    }
    unsigned int w0 = (unsigned int)f2bf(v[0]) | ((unsigned int)f2bf(v[1]) << 16);
    unsigned int w1 = (unsigned int)f2bf(v[2]) | ((unsigned int)f2bf(v[3]) << 16);
    unsigned int w2 = (unsigned int)f2bf(v[4]) | ((unsigned int)f2bf(v[5]) << 16);
    unsigned int w3 = (unsigned int)f2bf(v[6]) | ((unsigned int)f2bf(v[7]) << 16);
    uint4_ pack = {w0, w1, w2, w3};
    *(uint4_*)(fb + (size_t)row * K_PAD + f0) = pack;
}

// ---------------------------------------------------------------------------
// k0: Wt[c][k] = bf16(W1[k][c]), zero-padded to K_PAD.
// ---------------------------------------------------------------------------
__global__ __launch_bounds__(256) void k0_transpose(
    const float* __restrict__ W1, unsigned short* __restrict__ Wt)
{
    __shared__ unsigned short sm[64][NH];
    const int t = threadIdx.x;
    const int kbase = blockIdx.x * 64;

    for (int r = t >> 7; r < 64; r += 2) {
        const int k = kbase + r;
        const int c = t & (NH - 1);
        sm[r][c] = f2bf(k < IN_FEATS ? W1[(size_t)k * NH + c] : 0.f);
    }
    __syncthreads();

    const int c  = t >> 1;
    const int ko = (t & 1) * 32;
    unsigned short* dst = Wt + (size_t)c * K_PAD + kbase + ko;
    #pragma unroll
    for (int i = 0; i < 32; i += 8) {
        bf16x8 v;
        #pragma unroll
        for (int e = 0; e < 8; ++e) v[e] = (short)sm[ko + i + e][c];
        *(bf16x8*)(dst + i) = v;
    }
}

// ---------------------------------------------------------------------------
// k1_fused: gather-mean from L3-resident bf16 table -> 16-row LDS A-tile
// (XOR-swizzled) -> MFMA (B from global Wt) -> h1cat = [h, relu(h)] bf16.
// 256 thr / 4 waves; wave gathers 4 rows (one 16B load per neighbor-row),
// then computes 16 rows x 32 cols. ~16 waves/CU.
// ---------------------------------------------------------------------------
__global__ __launch_bounds__(256, 4) void k1_fused(
    const unsigned short* __restrict__ fb,    // [N0, K_PAD] bf16
    const int*   __restrict__ src0,           // [N1, FANOUT]
    const unsigned short* __restrict__ Wt,    // [NH, K_PAD] bf16
    const float* __restrict__ b1,             // [NH]
    unsigned short* __restrict__ h1cat)       // [N1, 2*NH] bf16
{
    __shared__ unsigned short A[ROWS * K_PAD];  // 16 KB, swizzled rows

    const int tid  = threadIdx.x;
    const int lane = tid & 63;
    const int wv   = tid >> 6;                // 0..3
    const int l15  = lane & 15;
    const int lq   = lane >> 4;               // 0..3
    const int rowbase = blockIdx.x * ROWS;
    const int f0 = lane * 8;                  // element offset within padded row

    // ---- Phase A: gather-mean, 4 rows per wave, one bf16x8 per neighbor ----
    #pragma unroll
    for (int r = 0; r < 4; ++r) {
        const int rl  = wv * 4 + r;
        const int row = rowbase + rl;
        float acc[8] = {0.f,0.f,0.f,0.f,0.f,0.f,0.f,0.f};
        if (row < N1) {
            const int rb = __builtin_amdgcn_readfirstlane(row) * FANOUT;
            #pragma unroll
            for (int j = 0; j < FANOUT; ++j) {
                const int nb = src0[rb + j];
                uint4_ v = *(const uint4_*)(fb + (size_t)nb * K_PAD + f0);
                acc[0] += bflo(v.x); acc[1] += bfhi(v.x);
                acc[2] += bflo(v.y); acc[3] += bfhi(v.y);
                acc[4] += bflo(v.z); acc[5] += bfhi(v.z);
                acc[6] += bflo(v.w); acc[7] += bfhi(v.w);
            }
        }
        unsigned int w0 = (unsigned int)f2bf(acc[0] * 0.0625f) | ((unsigned int)f2bf(acc[1] * 0.0625f) << 16);
        unsigned int w1 = (unsigned int)f2bf(acc[2] * 0.0625f) | ((unsigned int)f2bf(acc[3] * 0.0625f) << 16);
        unsigned int w2 = (unsigned int)f2bf(acc[4] * 0.0625f) | ((unsigned int)f2bf(acc[5] * 0.0625f) << 16);
        unsigned int w3 = (unsigned int)f2bf(acc[6] * 0.0625f) | ((unsigned int)f2bf(acc[7] * 0.0625f) << 16);
        uint4_ pack = {w0, w1, w2, w3};
        const int boff = rl * 1024 + ((f0 * 2) ^ ((rl & 7) << 4));   // byte offset
        *(uint4_*)((char*)A + boff) = pack;
    }
    __syncthreads();

    // ---- Phase B: all 16 rows x 32 cols per wave (cols wv*32..wv*32+31) ----
    f32x4 acc2[2];
    acc2[0] = (f32x4){0.f,0.f,0.f,0.f};
    acc2[1] = (f32x4){0.f,0.f,0.f,0.f};

    const int arow_base = l15 * 1024;
    const int aswz = (l15 & 7) << 4;

    #pragma unroll 4
    for (int kk = 0; kk < 16; ++kk) {
        const int ke = kk * 32 + lq * 8;      // element offset in [0, K_PAD)
        bf16x8 a = *(const bf16x8*)((const char*)A + arow_base + ((ke * 2) ^ aswz));
        #pragma unroll
        for (int nt = 0; nt < 2; ++nt) {
            const int col = wv * 32 + nt * 16 + l15;
            bf16x8 b = *(const bf16x8*)(Wt + (size_t)col * K_PAD + ke);
            acc2[nt] = __builtin_amdgcn_mfma_f32_16x16x32_bf16(a, b, acc2[nt], 0, 0, 0);
        }
    }

    // ---- Epilogue: bias + concat(h, relu(h)) ----
    #pragma unroll
    for (int nt = 0; nt < 2; ++nt) {
        const int col  = wv * 32 + nt * 16 + l15;
        const float bias = b1[col];
        #pragma unroll
        for (int rr = 0; rr < 4; ++rr) {
            const int row = rowbase + lq * 4 + rr;
            if (row < N1) {
                const float h = acc2[nt][rr] + bias;
                h1cat[(size_t)row * 256 + col]       = f2bf(h);
                h1cat[(size_t)row * 256 + 128 + col] = f2bf(h > 0.f ? h : 0.f);
            }
        }
    }
}

// ---------------------------------------------------------------------------
// k2: gather-mean over bf16 h1cat + f32 GEMM [8x256]@[256x47] + bias.
// ---------------------------------------------------------------------------
__global__ __launch_bounds__(256) void k2_fused(
    const unsigned short* __restrict__ h1cat, // [N1, 256] bf16
    const int*   __restrict__ src1,           // [N2, FANOUT]
    const float* __restrict__ W2,             // [256, NC]
    const float* __restrict__ b2,             // [NC]
    float*       __restrict__ out)            // [N2, NC]
{
    __shared__ float sm[8][256];

    const int tid = threadIdx.x;
    const int r   = tid >> 5;
    const int s   = tid & 31;
    const int row = blockIdx.x * 8 + r;

    float acc[8] = {0.f,0.f,0.f,0.f,0.f,0.f,0.f,0.f};
    #pragma unroll
    for (int j = 0; j < FANOUT; ++j) {
        const int nb = src1[row * FANOUT + j];
        uint4_ v = *(const uint4_*)(h1cat + (size_t)nb * 256 + s * 8);
        acc[0] += bflo(v.x); acc[1] += bfhi(v.x);
        acc[2] += bflo(v.y); acc[3] += bfhi(v.y);
        acc[4] += bflo(v.z); acc[5] += bfhi(v.z);
        acc[6] += bflo(v.w); acc[7] += bfhi(v.w);
    }
    #pragma unroll
    for (int e = 0; e < 8; ++e) sm[r][s * 8 + e] = acc[e] * 0.0625f;
    __syncthreads();

    const int c0 = s, c1 = s + 32;
    float o0 = b2[c0];
    float o1 = (c1 < NC) ? b2[c1] : 0.f;
    for (int k = 0; k < 256; k += 4) {
        f32x4 mv = *(const f32x4*)&sm[r][k];
        #pragma unroll
        for (int e = 0; e < 4; ++e) {
            const float* wrow = W2 + (size_t)(k + e) * NC;
            o0 += mv[e] * wrow[c0];
            if (c1 < NC) o1 += mv[e] * wrow[c1];
        }
    }
    out[(size_t)row * NC + c0] = o0;
    if (c1 < NC) out[(size_t)row * NC + c1] = o1;
}

extern "C" void kernel_launch(void* const* d_in, const int* in_sizes, int n_in,
                              void* d_out, int out_size, void* d_ws, size_t ws_size,
                              hipStream_t stream)
{
    const float* features = (const float*)d_in[0];
    const int*   src0     = (const int*)  d_in[1];
    const int*   src1     = (const int*)  d_in[2];
    const float* W1       = (const float*)d_in[3];
    const float* b1       = (const float*)d_in[4];
    const float* W2       = (const float*)d_in[5];
    const float* b2       = (const float*)d_in[6];
    float*       out      = (float*)d_out;

    unsigned short* fb    = (unsigned short*)d_ws;          // [N0][K_PAD] bf16 = 204.8 MB
    unsigned short* Wt    = fb + (size_t)N0 * K_PAD;        // [NH][K_PAD]  = 128 KB
    unsigned short* h1cat = Wt + (size_t)NH * K_PAD;        // [N1][256] bf16 = 12.8 MB

    hipLaunchKernelGGL(k_conv, dim3(N0 / 4), dim3(256), 0, stream, features, fb);
    hipLaunchKernelGGL(k0_transpose, dim3(K_PAD / 64), dim3(256), 0, stream, W1, Wt);
    hipLaunchKernelGGL(k1_fused, dim3((N1 + ROWS - 1) / ROWS), dim3(256), 0, stream,
                       fb, src0, Wt, b1, h1cat);
    hipLaunchKernelGGL(k2_fused, dim3(N2 / 8), dim3(256), 0, stream,
                       h1cat, src1, W2, b2, out);
}